// Round 2
// baseline (358.884 us; speedup 1.0000x reference)
//
#include <hip/hip_runtime.h>

// LeakyIntegrator: T=4096 scan over B=8192 columns, fp32. x is EXACTLY {0,1}.
// Algebraic reduction (round 1): m_t = d*(m_{t-1}+x_t) and
//   na1_t = m_{t-1} (EXACT), na0_t = S_t - m_{t-1} with S_t = d(1-d^t)/(1-d),
//   n10_t = m_t - n11_t  => only TWO data-dependent states (m, n11).
// Round 2: ONE kernel, decoupled chunk-lookback (no scan kernel, no bits
// round-trip, phases pipelined across blocks):
//   block (c,s): local scan (mask stays in regs) -> publish locals + flag ->
//   wait predecessors -> fold their locals (ascending, same fp ops as the old
//   scan_kernel) -> rescan chunk from incoming state, write predictions.
// Residency: 512 blocks x 256 thr, ~130 VGPR, 0 LDS => 2 blocks/CU on 256 CUs,
// all blocks resident before any spin => no deadlock.
// ws layout: [0,2MiB) m locals [NCHUNK][B_DIM]; [2,4MiB) n11 locals;
//            at 4MiB: flags int[NCHUNK][NSLAB] (memset to 0 each launch).

constexpr int T_DIM  = 4096;
constexpr int B_DIM  = 8192;
constexpr int NCHUNK = 64;
constexpr int CLEN   = T_DIM / NCHUNK;        // 64
constexpr int VEC    = 4;                     // columns per thread (float4)
constexpr int UNROLL = 8;                     // rows per load batch
constexpr int BLOCK  = 256;
constexpr int NSLAB  = B_DIM / (BLOCK * VEC); // 8

typedef float v4f __attribute__((ext_vector_type(4)));
typedef unsigned long long u64;

__global__ __launch_bounds__(BLOCK) void fused_kernel(
    const float* __restrict__ x, const float* __restrict__ dptr,
    float* __restrict__ ws, float* __restrict__ out)
{
    const float d = *dptr;
    float dL = d;                              // d^64
    #pragma unroll
    for (int i = 0; i < 6; ++i) dL = dL * dL;

    const int  c  = blockIdx.y;                // chunk
    const int  s  = blockIdx.x;                // column slab
    const int  b0 = s * (BLOCK * VEC) + (int)threadIdx.x * VEC;
    const long t0 = (long)c * CLEN;

    // x value just before this chunk (drives prev-bit and n11 at k=0)
    float pinit[VEC];
    if (c == 0) {
        #pragma unroll
        for (int j = 0; j < VEC; ++j) pinit[j] = 0.0f;
    } else {
        const v4f pv = *reinterpret_cast<const v4f*>(x + (t0 - 1) * B_DIM + b0);
        #pragma unroll
        for (int j = 0; j < VEC; ++j) pinit[j] = pv[j];
    }

    // ---- phase 1: chunk-local scan from zero, bit-pack x into registers ----
    float m[VEC]   = {0.f, 0.f, 0.f, 0.f};
    float n11[VEC] = {0.f, 0.f, 0.f, 0.f};
    u64   mask[VEC] = {0ull, 0ull, 0ull, 0ull};
    float prev[VEC];
    #pragma unroll
    for (int j = 0; j < VEC; ++j) prev[j] = pinit[j];

    const float* p = x + t0 * B_DIM + b0;
    v4f A[UNROLL], Bv[UNROLL];
    #pragma unroll
    for (int u = 0; u < UNROLL; ++u)
        A[u] = *reinterpret_cast<const v4f*>(p + (size_t)u * B_DIM);

    auto compute = [&](const v4f* buf, int kbase) {
        #pragma unroll
        for (int u = 0; u < UNROLL; ++u) {
            const int k = kbase + u;
            #pragma unroll
            for (int j = 0; j < VEC; ++j) {
                const float xt = buf[u][j];
                mask[j] |= (u64)(unsigned)xt << k;   // xt is exactly 0.0 or 1.0
                m[j]   = d * (m[j] + xt);
                n11[j] = d * (n11[j] + xt * prev[j]);
                prev[j] = xt;
            }
        }
    };

    #pragma unroll
    for (int kk = 0; kk < CLEN; kk += 2 * UNROLL) {
        #pragma unroll
        for (int u = 0; u < UNROLL; ++u)
            Bv[u] = *reinterpret_cast<const v4f*>(p + (size_t)(kk + UNROLL + u) * B_DIM);
        compute(A, kk);
        if (kk + 2 * UNROLL < CLEN) {               // compile-time after unroll
            #pragma unroll
            for (int u = 0; u < UNROLL; ++u)
                A[u] = *reinterpret_cast<const v4f*>(p + (size_t)(kk + 2 * UNROLL + u) * B_DIM);
        }
        compute(Bv, kk + UNROLL);
    }

    // ---- phase 2: publish locals, release flag ----
    {
        float* wm = ws + (size_t)c * B_DIM + b0;
        v4f mv, nv;
        #pragma unroll
        for (int j = 0; j < VEC; ++j) { mv[j] = m[j]; nv[j] = n11[j]; }
        *reinterpret_cast<v4f*>(wm)                          = mv;
        *reinterpret_cast<v4f*>(wm + (size_t)NCHUNK * B_DIM) = nv;
    }
    __threadfence();                 // make locals visible at agent scope
    __syncthreads();
    int* flags = reinterpret_cast<int*>(ws + (size_t)2 * NCHUNK * B_DIM);
    if (threadIdx.x == 0)
        __hip_atomic_store(&flags[c * NSLAB + s], 1,
                           __ATOMIC_RELEASE, __HIP_MEMORY_SCOPE_AGENT);

    // ---- phase 3: wait + fold predecessors' locals (ascending == old scan) ----
    float sm[VEC] = {0.f, 0.f, 0.f, 0.f};
    float sn[VEC] = {0.f, 0.f, 0.f, 0.f};
    if (c > 0) {
        if ((int)threadIdx.x < c) {                 // lane-per-flag, one wave covers all
            const int* f = &flags[(int)threadIdx.x * NSLAB + s];
            while (__hip_atomic_load(f, __ATOMIC_RELAXED,
                                     __HIP_MEMORY_SCOPE_AGENT) == 0)
                __builtin_amdgcn_s_sleep(8);
        }
        __syncthreads();
        __threadfence();             // acquire side: order fold loads after flags

        const float* lm = ws + b0;
        const float* ln = ws + (size_t)NCHUNK * B_DIM + b0;
        int cp = 0;
        for (; cp + 4 <= c; cp += 4) {              // grouped for load ILP
            v4f a0 = *reinterpret_cast<const v4f*>(lm + (size_t)(cp + 0) * B_DIM);
            v4f a1 = *reinterpret_cast<const v4f*>(lm + (size_t)(cp + 1) * B_DIM);
            v4f a2 = *reinterpret_cast<const v4f*>(lm + (size_t)(cp + 2) * B_DIM);
            v4f a3 = *reinterpret_cast<const v4f*>(lm + (size_t)(cp + 3) * B_DIM);
            v4f e0 = *reinterpret_cast<const v4f*>(ln + (size_t)(cp + 0) * B_DIM);
            v4f e1 = *reinterpret_cast<const v4f*>(ln + (size_t)(cp + 1) * B_DIM);
            v4f e2 = *reinterpret_cast<const v4f*>(ln + (size_t)(cp + 2) * B_DIM);
            v4f e3 = *reinterpret_cast<const v4f*>(ln + (size_t)(cp + 3) * B_DIM);
            #pragma unroll
            for (int j = 0; j < VEC; ++j) {
                sm[j] = dL * sm[j] + a0[j];  sn[j] = dL * sn[j] + e0[j];
                sm[j] = dL * sm[j] + a1[j];  sn[j] = dL * sn[j] + e1[j];
                sm[j] = dL * sm[j] + a2[j];  sn[j] = dL * sn[j] + e2[j];
                sm[j] = dL * sm[j] + a3[j];  sn[j] = dL * sn[j] + e3[j];
            }
        }
        for (; cp < c; ++cp) {
            v4f a = *reinterpret_cast<const v4f*>(lm + (size_t)cp * B_DIM);
            v4f e = *reinterpret_cast<const v4f*>(ln + (size_t)cp * B_DIM);
            #pragma unroll
            for (int j = 0; j < VEC; ++j) {
                sm[j] = dL * sm[j] + a[j];
                sn[j] = dL * sn[j] + e[j];
            }
        }
    }

    // ---- phase 4: rescan chunk from incoming state, emit predictions ----
    // incoming na_sum = d*(1 - d^(64c)) / (1-d); 1-d exact for d in [0.5,1)
    float dLc = 1.f, sq = dL;
    int cc = c;
    #pragma unroll
    for (int i = 0; i < 6; ++i) { if (cc & 1) dLc *= sq; sq *= sq; cc >>= 1; }
    float na = d * (1.f - dLc) / (1.f - d);

    float M[VEC], N11[VEC];
    bool  pb[VEC];
    #pragma unroll
    for (int j = 0; j < VEC; ++j) {
        M[j] = sm[j]; N11[j] = sn[j]; pb[j] = (pinit[j] != 0.0f);
    }

    float* q = out + (size_t)c * CLEN * B_DIM + b0;
    for (int kk = 0; kk < CLEN; kk += UNROLL) {
        #pragma unroll
        for (int u = 0; u < UNROLL; ++u) {
            const int k = kk + u;
            na = d * (na + 1.f);
            float pr[VEC];
            #pragma unroll
            for (int j = 0; j < VEC; ++j) {
                const bool  xb = (mask[j] >> k) & 1ull;
                const float mo = M[j];               // = na1_t (exact identity)
                M[j]   = d * (mo + (xb ? 1.f : 0.f));
                N11[j] = d * (N11[j] + ((xb && pb[j]) ? 1.f : 0.f));
                const float num = xb ? (N11[j] + 1.f) : (M[j] - N11[j] + 1.f);
                const float den = xb ? (mo + 2.f)     : (na - mo + 2.f);
                pr[j] = num * __builtin_amdgcn_rcpf(den);   // ONE rcp per element
                pb[j] = xb;
            }
            v4f ov;
            #pragma unroll
            for (int j = 0; j < VEC; ++j) ov[j] = pr[j];
            __builtin_nontemporal_store(ov, reinterpret_cast<v4f*>(q + (size_t)u * B_DIM));
        }
        q += (size_t)UNROLL * B_DIM;
    }
}

extern "C" void kernel_launch(void* const* d_in, const int* in_sizes, int n_in,
                              void* d_out, int out_size, void* d_ws, size_t ws_size,
                              hipStream_t stream) {
    const float* x  = (const float*)d_in[0];
    const float* dr = (const float*)d_in[1];
    float* ws  = (float*)d_ws;    // needs 4 MiB locals + 2 KiB flags
    float* out = (float*)d_out;

    // ws is poisoned by the harness: zero the lookback flags (tiny, capture-legal)
    void* flags = (void*)((char*)d_ws + (size_t)2 * NCHUNK * B_DIM * sizeof(float));
    hipMemsetAsync(flags, 0, NCHUNK * NSLAB * sizeof(int), stream);

    dim3 blk(BLOCK);
    dim3 grid(NSLAB, NCHUNK);   // (8, 64) = 512 blocks
    fused_kernel<<<grid, blk, 0, stream>>>(x, dr, ws, out);
}

// Round 3
// 236.267 us; speedup vs baseline: 1.5190x; 1.5190x over previous
//
#include <hip/hip_runtime.h>

// LeakyIntegrator: T=4096 scan over B=8192 columns, fp32. x is EXACTLY {0,1}.
// Algebraic reduction: with m_t = d*(m_{t-1}+x_t)   (= n10+n11, decayed ones),
//   na1_t = m_{t-1}                       (EXACT identity, same fp op sequence)
//   na0_t = S_t - m_{t-1},  S_t = d*(S_{t-1}+1) = d(1-d^t)/(1-d)   (data-independent)
//   n10_t = m_t - n11_t
// => only TWO data-dependent states (m, n11) + bit-packed x.
// Round 3: 3-kernel structure (round-2 fused lookback regressed 2.5x: agent-scope
// fences = per-block L2 writeback/invalidate on non-coherent XCD L2s -> 1 TB/s).
// Fix vs round 1: VEC=2 everywhere -> 1024 blocks = 4 blocks/CU = 16 waves/CU
// (round-1 VEC=4 gave only 2 blocks/CU: ~2 MB in flight vs the ~2.5 MB BW*latency
// product -> partial read x at ~4-5 TB/s). Scan uses 64-thread blocks (256 CUs).
// ws layout (8 MiB):
//   [0, 2 MiB)  : m   locals [NCHUNK][B_DIM] float
//   [2, 4 MiB)  : n11 locals [NCHUNK][B_DIM] float
//   [4, 8 MiB)  : packed x bits [NCHUNK][B_DIM] u64

constexpr int T_DIM  = 4096;
constexpr int B_DIM  = 8192;
constexpr int NCHUNK = 64;
constexpr int CLEN   = T_DIM / NCHUNK;   // 64
constexpr int VEC    = 2;                // columns per thread
constexpr int UNROLL = 8;                // rows per load batch
constexpr int BLOCK  = 256;

typedef float v2f __attribute__((ext_vector_type(2)));
typedef unsigned long long u64;
typedef u64 v2u __attribute__((ext_vector_type(2)));

__global__ __launch_bounds__(BLOCK) void partial_kernel(
    const float* __restrict__ x, const float* __restrict__ dptr,
    float* __restrict__ ws)
{
    const float d  = *dptr;
    const int   c  = blockIdx.y;
    const int   b0 = (blockIdx.x * BLOCK + (int)threadIdx.x) * VEC;
    const long  t0 = (long)c * CLEN;

    float prev[VEC];
    if (c == 0) {
        prev[0] = prev[1] = 0.0f;
    } else {
        const v2f pv = *reinterpret_cast<const v2f*>(x + (t0 - 1) * B_DIM + b0);
        prev[0] = pv[0]; prev[1] = pv[1];
    }

    float m[VEC]   = {0.f, 0.f};
    float n11[VEC] = {0.f, 0.f};
    u64   mask[VEC] = {0ull, 0ull};

    const float* p = x + t0 * B_DIM + b0;

    // two-batch software pipeline: next batch's loads in flight while current
    // batch is consumed. Static indexing only (named A/Bv), full unroll.
    v2f A[UNROLL], Bv[UNROLL];
    #pragma unroll
    for (int u = 0; u < UNROLL; ++u)
        A[u] = *reinterpret_cast<const v2f*>(p + (size_t)u * B_DIM);

    auto compute = [&](const v2f* buf, int kbase) {
        #pragma unroll
        for (int u = 0; u < UNROLL; ++u) {
            const int k = kbase + u;
            #pragma unroll
            for (int j = 0; j < VEC; ++j) {
                const float xt = buf[u][j];
                mask[j] |= (u64)(unsigned)xt << k;   // xt is exactly 0.0 or 1.0
                m[j]   = d * (m[j] + xt);
                n11[j] = d * (n11[j] + xt * prev[j]);
                prev[j] = xt;
            }
        }
    };

    #pragma unroll
    for (int kk = 0; kk < CLEN; kk += 2 * UNROLL) {
        #pragma unroll
        for (int u = 0; u < UNROLL; ++u)
            Bv[u] = *reinterpret_cast<const v2f*>(p + (size_t)(kk + UNROLL + u) * B_DIM);
        compute(A, kk);
        if (kk + 2 * UNROLL < CLEN) {               // compile-time after unroll
            #pragma unroll
            for (int u = 0; u < UNROLL; ++u)
                A[u] = *reinterpret_cast<const v2f*>(p + (size_t)(kk + 2 * UNROLL + u) * B_DIM);
        }
        compute(Bv, kk + UNROLL);
    }

    // locals + bits are consumed by the NEXT kernels (cross-XCD, via L3):
    // nontemporal stores keep L2 clean during the streaming read phase.
    float* wm = ws + (size_t)c * B_DIM + b0;
    v2f mv, nv;
    mv[0] = m[0];   mv[1] = m[1];
    nv[0] = n11[0]; nv[1] = n11[1];
    __builtin_nontemporal_store(mv, reinterpret_cast<v2f*>(wm));
    __builtin_nontemporal_store(nv, reinterpret_cast<v2f*>(wm + (size_t)NCHUNK * B_DIM));

    u64* bits = reinterpret_cast<u64*>(ws + (size_t)2 * NCHUNK * B_DIM);
    v2u bm; bm[0] = mask[0]; bm[1] = mask[1];
    __builtin_nontemporal_store(bm, reinterpret_cast<v2u*>(&bits[(size_t)c * B_DIM + b0]));
}

// One thread per (state, column): 2*8192 = 16384 threads, 64-thread blocks so
// all 256 CUs participate. All 64 chunk-local loads hoisted before the fold.
__global__ __launch_bounds__(64) void scan_kernel(
    const float* __restrict__ dptr, float* __restrict__ ws)
{
    float dL = *dptr;                 // d^CLEN, CLEN = 64 = 2^6
    #pragma unroll
    for (int i = 0; i < 6; ++i) dL = dL * dL;

    const int tid = blockIdx.x * 64 + (int)threadIdx.x;   // [0, 2*B)
    float* p = ws + (size_t)(tid >> 13) * NCHUNK * B_DIM + (tid & (B_DIM - 1));

    float l[NCHUNK];
    #pragma unroll
    for (int c = 0; c < NCHUNK; ++c) l[c] = p[(size_t)c * B_DIM];

    float s = 0.f;
    #pragma unroll
    for (int c = 0; c < NCHUNK; ++c) {
        p[(size_t)c * B_DIM] = s;     // incoming state for chunk c
        s = dL * s + l[c];
    }
}

__global__ __launch_bounds__(BLOCK) void final_kernel(
    const float* __restrict__ dptr, const float* __restrict__ ws,
    float* __restrict__ out)
{
    const float d = *dptr;
    float dL = d;
    #pragma unroll
    for (int i = 0; i < 6; ++i) dL = dL * dL;                  // d^64

    const int c  = blockIdx.y;
    const int b0 = (blockIdx.x * BLOCK + (int)threadIdx.x) * VEC;

    const float* w = ws + (size_t)c * B_DIM + b0;
    const v2f mi = *reinterpret_cast<const v2f*>(w);
    const v2f ni = *reinterpret_cast<const v2f*>(w + (size_t)NCHUNK * B_DIM);
    float m[VEC]   = {mi[0], mi[1]};
    float n11[VEC] = {ni[0], ni[1]};

    // incoming na_sum = d*(1 - d^(64c)) / (1-d); 1-d is EXACT for d in [0.5,1)
    float dLc = 1.f, sq = dL;
    int cc = c;
    #pragma unroll
    for (int i = 0; i < 6; ++i) { if (cc & 1) dLc *= sq; sq *= sq; cc >>= 1; }
    float na = d * (1.f - dLc) / (1.f - d);

    const u64* bits = reinterpret_cast<const u64*>(ws + (size_t)2 * NCHUNK * B_DIM);
    const v2u bm = *reinterpret_cast<const v2u*>(&bits[(size_t)c * B_DIM + b0]);
    u64 mask[VEC] = {bm[0], bm[1]};

    bool pb[VEC];
    if (c == 0) {
        pb[0] = pb[1] = false;
    } else {
        const v2u pm = *reinterpret_cast<const v2u*>(&bits[(size_t)(c - 1) * B_DIM + b0]);
        pb[0] = (pm[0] >> 63) & 1ull;
        pb[1] = (pm[1] >> 63) & 1ull;
    }

    float* q = out + (size_t)c * CLEN * B_DIM + b0;
    for (int kk = 0; kk < CLEN; kk += UNROLL) {
        #pragma unroll
        for (int u = 0; u < UNROLL; ++u) {
            const int k = kk + u;
            na = d * (na + 1.f);                     // uniform, 1 op per row
            float pr[VEC];
            #pragma unroll
            for (int j = 0; j < VEC; ++j) {
                const bool  xb = (mask[j] >> k) & 1ull;
                const float mo = m[j];               // = na1_t (exact identity)
                m[j]   = d * (mo + (xb ? 1.f : 0.f));
                n11[j] = d * (n11[j] + ((xb && pb[j]) ? 1.f : 0.f));
                const float num = xb ? (n11[j] + 1.f) : (m[j] - n11[j] + 1.f);
                const float den = xb ? (mo + 2.f)     : (na - mo + 2.f);
                pr[j] = num * __builtin_amdgcn_rcpf(den);   // ONE rcp per element
                pb[j] = xb;
            }
            v2f ov; ov[0] = pr[0]; ov[1] = pr[1];
            __builtin_nontemporal_store(ov, reinterpret_cast<v2f*>(q + (size_t)u * B_DIM));
        }
        q += (size_t)UNROLL * B_DIM;
    }
}

extern "C" void kernel_launch(void* const* d_in, const int* in_sizes, int n_in,
                              void* d_out, int out_size, void* d_ws, size_t ws_size,
                              hipStream_t stream) {
    const float* x  = (const float*)d_in[0];
    const float* dr = (const float*)d_in[1];
    float* ws  = (float*)d_ws;    // needs 8 MiB
    float* out = (float*)d_out;

    dim3 blk(BLOCK);
    dim3 grid1(B_DIM / VEC / BLOCK, NCHUNK);   // (16, 64) = 1024 blocks
    partial_kernel<<<grid1, blk, 0, stream>>>(x, dr, ws);
    scan_kernel<<<(2 * B_DIM) / 64, dim3(64), 0, stream>>>(dr, ws);
    final_kernel<<<grid1, blk, 0, stream>>>(dr, ws, out);
}